// Round 2
// baseline (1341.165 us; speedup 1.0000x reference)
//
#include <hip/hip_runtime.h>
#include <math.h>

#define BB 2
#define SS 2048
#define DD 1024
#define HH 16
#define HD 64

// ---------------- GEMM: C = X @ W^T + bias ----------------
// X: (M=4096, K=1024) row-major, W: (N=1024, K=1024) row-major.
// split=1: write C[m][n] to out[b][h][s][hd] (b=m/S, s=m%S, h=n/64, hd=n%64)
// split=0: write C[m][n] to out[m][n]
#define GM 128
#define GN 64
#define GK 16

__global__ __launch_bounds__(256)
void gemm_bias_kernel(const float* __restrict__ X, const float* __restrict__ W,
                      const float* __restrict__ bias, float* __restrict__ C,
                      int split)
{
    __shared__ float Xs[GK][GM + 4];   // stride 132 floats (528B, 16B-aligned rows)
    __shared__ float Ws[GK][GN + 4];   // stride 68 floats (272B, 16B-aligned rows)

    const int tid = threadIdx.x;
    const int tx = tid & 15;    // n micro (4 cols)
    const int ty = tid >> 4;    // m micro (8 rows)
    const int m0 = blockIdx.y * GM;
    const int n0 = blockIdx.x * GN;

    float acc[8][4];
#pragma unroll
    for (int i = 0; i < 8; ++i)
#pragma unroll
        for (int j = 0; j < 4; ++j) acc[i][j] = 0.0f;

    for (int k0 = 0; k0 < DD; k0 += GK) {
        // stage X tile (128x16) transposed -> Xs[k][m]; 512 float4, 2 per thread
#pragma unroll
        for (int t = 0; t < 2; ++t) {
            const int idx = tid + t * 256;
            const int row = idx >> 2;
            const int k4  = (idx & 3) << 2;
            const float4 v = *(const float4*)(X + (size_t)(m0 + row) * DD + k0 + k4);
            Xs[k4 + 0][row] = v.x;
            Xs[k4 + 1][row] = v.y;
            Xs[k4 + 2][row] = v.z;
            Xs[k4 + 3][row] = v.w;
        }
        {   // stage W tile (64x16) transposed -> Ws[k][n]; 256 float4, 1 per thread
            const int row = tid >> 2;
            const int k4  = (tid & 3) << 2;
            const float4 v = *(const float4*)(W + (size_t)(n0 + row) * DD + k0 + k4);
            Ws[k4 + 0][row] = v.x;
            Ws[k4 + 1][row] = v.y;
            Ws[k4 + 2][row] = v.z;
            Ws[k4 + 3][row] = v.w;
        }
        __syncthreads();

#pragma unroll
        for (int k = 0; k < GK; ++k) {
            const float4 a0 = *(const float4*)&Xs[k][ty * 8];
            const float4 a1 = *(const float4*)&Xs[k][ty * 8 + 4];
            const float4 bv = *(const float4*)&Ws[k][tx * 4];
            const float a[8] = {a0.x, a0.y, a0.z, a0.w, a1.x, a1.y, a1.z, a1.w};
            const float bb[4] = {bv.x, bv.y, bv.z, bv.w};
#pragma unroll
            for (int i = 0; i < 8; ++i) {
#pragma unroll
                for (int j = 0; j < 4; ++j)
                    acc[i][j] = fmaf(a[i], bb[j], acc[i][j]);
            }
        }
        __syncthreads();
    }

    const float4 bv = *(const float4*)(bias + n0 + tx * 4);
    if (split) {
        const int h = n0 >> 6;   // GN==64 -> one head per block column
#pragma unroll
        for (int i = 0; i < 8; ++i) {
            const int m = m0 + ty * 8 + i;
            const int b = m >> 11;          // /S
            const int s = m & (SS - 1);
            float4 o;
            o.x = acc[i][0] + bv.x;
            o.y = acc[i][1] + bv.y;
            o.z = acc[i][2] + bv.z;
            o.w = acc[i][3] + bv.w;
            *(float4*)(C + (size_t)((b * HH + h) * SS + s) * HD + tx * 4) = o;
        }
    } else {
#pragma unroll
        for (int i = 0; i < 8; ++i) {
            const int m = m0 + ty * 8 + i;
            float4 o;
            o.x = acc[i][0] + bv.x;
            o.y = acc[i][1] + bv.y;
            o.z = acc[i][2] + bv.z;
            o.w = acc[i][3] + bv.w;
            *(float4*)(C + (size_t)m * DD + n0 + tx * 4) = o;
        }
    }
}

// ---------------- Flash attention (fp32), Q/K/V in [B,H,S,HD] ----------------
// Out written as [B,S,D] (head-merged) for the final projection GEMM.
#define TQ 32
#define TK 64

__global__ __launch_bounds__(256)
void attn_kernel(const float* __restrict__ Q, const float* __restrict__ K,
                 const float* __restrict__ V, const int* __restrict__ mask,
                 float* __restrict__ O)
{
    __shared__ float Qt[HD][TQ + 2];   // transposed: Qt[d][q], stride 34
    __shared__ float Kt[HD][TK + 4];   // transposed: Kt[d][c], stride 68
    __shared__ float Vs[TK][HD + 4];   // natural:    Vs[k][d], stride 68
    __shared__ float Pt[TK][TQ + 2];   // transposed: Pt[c][q], stride 34
    __shared__ float pmax[8][TQ];
    __shared__ float psum[8][TQ];
    __shared__ float mrow[TQ];
    __shared__ float arow[TQ];
    __shared__ float linv[TQ];

    const int tid = threadIdx.x;
    const int tx = tid & 15;    // 4 cols of the 64-wide tile
    const int ty = tid >> 4;    // 2 rows of the 32-tall tile
    const int q0 = blockIdx.x * TQ;
    const int h  = blockIdx.y;
    const int b  = blockIdx.z;

    const float* Qbh = Q + (size_t)(b * HH + h) * SS * HD;
    const float* Kbh = K + (size_t)(b * HH + h) * SS * HD;
    const float* Vbh = V + (size_t)(b * HH + h) * SS * HD;

    // stage Q tile transposed (32 x 64) -> Qt[d][q]
#pragma unroll
    for (int t = 0; t < 2; ++t) {
        const int idx = tid + t * 256;
        const int r  = idx >> 4;          // 0..31
        const int d4 = (idx & 15) << 2;
        const float4 v = *(const float4*)(Qbh + (size_t)(q0 + r) * HD + d4);
        Qt[d4 + 0][r] = v.x;
        Qt[d4 + 1][r] = v.y;
        Qt[d4 + 2][r] = v.z;
        Qt[d4 + 3][r] = v.w;
    }

    float m_r = -INFINITY;   // row state, valid for tid < 32
    float l_r = 0.0f;
    float acc[2][4];
#pragma unroll
    for (int i = 0; i < 2; ++i)
#pragma unroll
        for (int j = 0; j < 4; ++j) acc[i][j] = 0.0f;

    const int sr = tid & 31;   // scan row
    const int sp = tid >> 5;   // scan partition (8 x 8 keys)

    for (int kt = 0; kt < SS / TK; ++kt) {
        const int k0 = kt * TK;
        __syncthreads();   // prev PV done before overwriting Kt/Vs/Pt

        // stage K transposed + V natural (64 x 64 each); 4 float4 pairs/thread
#pragma unroll
        for (int t = 0; t < 4; ++t) {
            const int idx = tid + t * 256;
            const int r  = idx >> 4;           // 0..63
            const int d4 = (idx & 15) << 2;
            const float4 kv = *(const float4*)(Kbh + (size_t)(k0 + r) * HD + d4);
            Kt[d4 + 0][r] = kv.x;
            Kt[d4 + 1][r] = kv.y;
            Kt[d4 + 2][r] = kv.z;
            Kt[d4 + 3][r] = kv.w;
            const float4 vv = *(const float4*)(Vbh + (size_t)(k0 + r) * HD + d4);
            *(float4*)&Vs[r][d4] = vv;
        }
        __syncthreads();

        // S = Q K^T (2x4 per thread)
        float s[2][4];
#pragma unroll
        for (int i = 0; i < 2; ++i)
#pragma unroll
            for (int j = 0; j < 4; ++j) s[i][j] = 0.0f;

#pragma unroll 16
        for (int d = 0; d < HD; ++d) {
            const float2 a = *(const float2*)&Qt[d][ty * 2];
            const float4 kv = *(const float4*)&Kt[d][tx * 4];
            s[0][0] = fmaf(a.x, kv.x, s[0][0]);
            s[0][1] = fmaf(a.x, kv.y, s[0][1]);
            s[0][2] = fmaf(a.x, kv.z, s[0][2]);
            s[0][3] = fmaf(a.x, kv.w, s[0][3]);
            s[1][0] = fmaf(a.y, kv.x, s[1][0]);
            s[1][1] = fmaf(a.y, kv.y, s[1][1]);
            s[1][2] = fmaf(a.y, kv.z, s[1][2]);
            s[1][3] = fmaf(a.y, kv.w, s[1][3]);
        }

        // scale + mask, write transposed scores to Pt[c][q]
        const int4 mv = *(const int4*)(mask + b * SS + k0 + tx * 4);
        const int mm[4] = {mv.x, mv.y, mv.z, mv.w};
#pragma unroll
        for (int j = 0; j < 4; ++j) {
            const float v0 = (mm[j] == 0) ? -1.0e9f : s[0][j] * 0.125f;
            const float v1 = (mm[j] == 0) ? -1.0e9f : s[1][j] * 0.125f;
            Pt[tx * 4 + j][ty * 2 + 0] = v0;
            Pt[tx * 4 + j][ty * 2 + 1] = v1;
        }
        __syncthreads();

        // partial max per row (8 threads per row, 8 keys each)
        {
            float pm = -INFINITY;
#pragma unroll
            for (int u = 0; u < 8; ++u) pm = fmaxf(pm, Pt[sp * 8 + u][sr]);
            pmax[sp][sr] = pm;
        }
        __syncthreads();

        if (tid < TQ) {
            float mt = m_r;
#pragma unroll
            for (int p = 0; p < 8; ++p) mt = fmaxf(mt, pmax[p][tid]);
            const float a = __expf(m_r - mt);   // exp(-inf - finite) = 0 on first tile
            m_r = mt;
            mrow[tid] = mt;
            arow[tid] = a;
        }
        __syncthreads();

        // exp + writeback + partial sum
        {
            const float mloc = mrow[sr];
            float ps = 0.0f;
#pragma unroll
            for (int u = 0; u < 8; ++u) {
                const float e = __expf(Pt[sp * 8 + u][sr] - mloc);
                Pt[sp * 8 + u][sr] = e;
                ps += e;
            }
            psum[sp][sr] = ps;
        }
        __syncthreads();

        if (tid < TQ) {
            float ssum = 0.0f;
#pragma unroll
            for (int p = 0; p < 8; ++p) ssum += psum[p][tid];
            l_r = l_r * arow[tid] + ssum;
        }

        // rescale accumulators and accumulate P @ V
        const float al0 = arow[ty * 2 + 0];
        const float al1 = arow[ty * 2 + 1];
#pragma unroll
        for (int j = 0; j < 4; ++j) { acc[0][j] *= al0; acc[1][j] *= al1; }

#pragma unroll 16
        for (int k = 0; k < TK; ++k) {
            const float2 a = *(const float2*)&Pt[k][ty * 2];
            const float4 v = *(const float4*)&Vs[k][tx * 4];
            acc[0][0] = fmaf(a.x, v.x, acc[0][0]);
            acc[0][1] = fmaf(a.x, v.y, acc[0][1]);
            acc[0][2] = fmaf(a.x, v.z, acc[0][2]);
            acc[0][3] = fmaf(a.x, v.w, acc[0][3]);
            acc[1][0] = fmaf(a.y, v.x, acc[1][0]);
            acc[1][1] = fmaf(a.y, v.y, acc[1][1]);
            acc[1][2] = fmaf(a.y, v.z, acc[1][2]);
            acc[1][3] = fmaf(a.y, v.w, acc[1][3]);
        }
    }

    if (tid < TQ) linv[tid] = 1.0f / l_r;
    __syncthreads();

    // write O as [B,S,D] with d = h*64 + dd
#pragma unroll
    for (int i = 0; i < 2; ++i) {
        const int q = ty * 2 + i;
        const float li = linv[q];
        float4 o;
        o.x = acc[i][0] * li;
        o.y = acc[i][1] * li;
        o.z = acc[i][2] * li;
        o.w = acc[i][3] * li;
        *(float4*)(O + (size_t)(b * SS + q0 + q) * DD + h * HD + tx * 4) = o;
    }
}

extern "C" void kernel_launch(void* const* d_in, const int* in_sizes, int n_in,
                              void* d_out, int out_size, void* d_ws, size_t ws_size,
                              hipStream_t stream) {
    const float* xq   = (const float*)d_in[0];
    const float* xk   = (const float*)d_in[1];
    const float* xv   = (const float*)d_in[2];
    const int*   mask = (const int*)d_in[3];
    const float* wq   = (const float*)d_in[4];
    const float* bq   = (const float*)d_in[5];
    const float* wk   = (const float*)d_in[6];
    const float* bk   = (const float*)d_in[7];
    const float* wv   = (const float*)d_in[8];
    const float* bv   = (const float*)d_in[9];
    const float* wo   = (const float*)d_in[10];
    const float* bo   = (const float*)d_in[11];
    float* out = (float*)d_out;

    float* ws = (float*)d_ws;
    const size_t n = (size_t)BB * SS * DD;   // 4,194,304 floats (16 MB)
    // Q-heads live in d_out (fully consumed by attn_kernel before the final
    // GEMM overwrites d_out — stream-ordered). d_ws holds K, V, Oa = 48 MB.
    float* Qh = out;
    float* Kh = ws;
    float* Vh = ws + n;
    float* Oa = ws + 2 * n;

    dim3 gg(DD / GN, (BB * SS) / GM);   // (16, 32)
    gemm_bias_kernel<<<gg, 256, 0, stream>>>(xq, wq, bq, Qh, 1);
    gemm_bias_kernel<<<gg, 256, 0, stream>>>(xk, wk, bk, Kh, 1);
    gemm_bias_kernel<<<gg, 256, 0, stream>>>(xv, wv, bv, Vh, 1);

    dim3 ga(SS / TQ, HH, BB);           // (64, 16, 2)
    attn_kernel<<<ga, 256, 0, stream>>>(Qh, Kh, Vh, mask, Oa);

    gemm_bias_kernel<<<gg, 256, 0, stream>>>(Oa, wo, bo, out, 0);
}

// Round 3
// 1045.497 us; speedup vs baseline: 1.2828x; 1.2828x over previous
//
#include <hip/hip_runtime.h>
#include <math.h>

#define BB 2
#define SS 2048
#define DD 1024
#define HH 16
#define HD 64

typedef short short8 __attribute__((ext_vector_type(8)));
typedef float floatx4 __attribute__((ext_vector_type(4)));

__device__ inline ushort f2bf_rne(float x) {
    union { float f; unsigned u; } v; v.f = x;
    unsigned r = v.u + 0x7FFFu + ((v.u >> 16) & 1u);
    return (ushort)(r >> 16);
}

// ---------------- Split-bf16 MFMA GEMM: C = X @ W^T + bias ----------------
// X: (M, K=1024) row-major fp32, W: (N=1024, K=1024) row-major fp32.
// x = hi + lo (both bf16); X@W^T ~= Xh Wh + Xh Wl + Xl Wh  (lo*lo ~2^-16, dropped)
// split=1: C[m][n] -> out[b][h][s][hd]; split=0: C[m][n] -> out[m][n]
#define BM 128
#define BN 64
#define BK 32
#define LDK 40   // k-stride in ushorts; (20t+4q)%32 covers all banks -> conflict-free b128

__global__ __launch_bounds__(256, 2)
void gemm_bias_mfma(const float* __restrict__ X, const float* __restrict__ W,
                    const float* __restrict__ bias, float* __restrict__ C,
                    int split)
{
    __shared__ ushort Ah[BM][LDK];
    __shared__ ushort Al[BM][LDK];
    __shared__ ushort Bh[BN][LDK];
    __shared__ ushort Bl[BN][LDK];

    const int tid  = threadIdx.x;
    const int lane = tid & 63;
    const int wave = tid >> 6;
    const int wr = wave >> 1;     // m half (64 rows)
    const int wc = wave & 1;      // n half (32 cols)
    const int lt = lane & 15;
    const int lq = lane >> 4;
    const int m0 = blockIdx.y * BM;
    const int n0 = blockIdx.x * BN;

    floatx4 acc[4][2];
#pragma unroll
    for (int mi = 0; mi < 4; ++mi)
#pragma unroll
        for (int ni = 0; ni < 2; ++ni) acc[mi][ni] = (floatx4)0.0f;

    // staging coords (fixed per thread)
    const int ar[4] = { (tid + 0*256) >> 3, (tid + 1*256) >> 3,
                        (tid + 2*256) >> 3, (tid + 3*256) >> 3 };
    const int ak = (tid & 7) * 4;

    for (int k0 = 0; k0 < DD; k0 += BK) {
        // global loads (before barrier, to overlap with prev MFMA tail)
        float4 av[4], bv[2];
#pragma unroll
        for (int t = 0; t < 4; ++t)
            av[t] = *(const float4*)(X + (size_t)(m0 + ar[t]) * DD + k0 + ak);
#pragma unroll
        for (int t = 0; t < 2; ++t)
            bv[t] = *(const float4*)(W + (size_t)(n0 + ar[t]) * DD + k0 + ak);

        __syncthreads();   // prev iteration's frag reads done

        // convert to hi/lo bf16 and stage
#pragma unroll
        for (int t = 0; t < 4; ++t) {
            const float x[4] = {av[t].x, av[t].y, av[t].z, av[t].w};
            ushort4 h, l;
            ushort* hp = (ushort*)&h; ushort* lp = (ushort*)&l;
#pragma unroll
            for (int j = 0; j < 4; ++j) {
                const ushort hh = f2bf_rne(x[j]);
                union { unsigned u; float f; } hv; hv.u = ((unsigned)hh) << 16;
                hp[j] = hh;
                lp[j] = f2bf_rne(x[j] - hv.f);
            }
            *(ushort4*)&Ah[ar[t]][ak] = h;
            *(ushort4*)&Al[ar[t]][ak] = l;
        }
#pragma unroll
        for (int t = 0; t < 2; ++t) {
            const float x[4] = {bv[t].x, bv[t].y, bv[t].z, bv[t].w};
            ushort4 h, l;
            ushort* hp = (ushort*)&h; ushort* lp = (ushort*)&l;
#pragma unroll
            for (int j = 0; j < 4; ++j) {
                const ushort hh = f2bf_rne(x[j]);
                union { unsigned u; float f; } hv; hv.u = ((unsigned)hh) << 16;
                hp[j] = hh;
                lp[j] = f2bf_rne(x[j] - hv.f);
            }
            *(ushort4*)&Bh[ar[t]][ak] = h;
            *(ushort4*)&Bl[ar[t]][ak] = l;
        }
        __syncthreads();   // staging visible

        // fragments: A[m=lt][k=lq*8+j], B[n=lt][k=lq*8+j]  (verified m89/m91 layout)
        short8 a_h[4], a_l[4], b_h[2], b_l[2];
#pragma unroll
        for (int mi = 0; mi < 4; ++mi) {
            const int row = wr * 64 + mi * 16 + lt;
            a_h[mi] = *(const short8*)&Ah[row][lq * 8];
            a_l[mi] = *(const short8*)&Al[row][lq * 8];
        }
#pragma unroll
        for (int ni = 0; ni < 2; ++ni) {
            const int row = wc * 32 + ni * 16 + lt;
            b_h[ni] = *(const short8*)&Bh[row][lq * 8];
            b_l[ni] = *(const short8*)&Bl[row][lq * 8];
        }

#pragma unroll
        for (int mi = 0; mi < 4; ++mi)
#pragma unroll
            for (int ni = 0; ni < 2; ++ni) {
                acc[mi][ni] = __builtin_amdgcn_mfma_f32_16x16x32_bf16(a_h[mi], b_h[ni], acc[mi][ni], 0, 0, 0);
                acc[mi][ni] = __builtin_amdgcn_mfma_f32_16x16x32_bf16(a_h[mi], b_l[ni], acc[mi][ni], 0, 0, 0);
                acc[mi][ni] = __builtin_amdgcn_mfma_f32_16x16x32_bf16(a_l[mi], b_h[ni], acc[mi][ni], 0, 0, 0);
            }
    }

    // epilogue: C/D layout col=lane&15, row=lq*4+reg (verified m89)
    const float bias0 = bias[n0 + wc * 32 + lt];
    const float bias1 = bias[n0 + wc * 32 + 16 + lt];
#pragma unroll
    for (int mi = 0; mi < 4; ++mi) {
#pragma unroll
        for (int ni = 0; ni < 2; ++ni) {
            const int n = n0 + wc * 32 + ni * 16 + lt;
            const float bb = ni ? bias1 : bias0;
#pragma unroll
            for (int r = 0; r < 4; ++r) {
                const int m = m0 + wr * 64 + mi * 16 + lq * 4 + r;
                const float val = acc[mi][ni][r] + bb;
                if (split) {
                    const int b = m >> 11;          // /S
                    const int s = m & (SS - 1);
                    const int h = n >> 6;
                    C[(size_t)((b * HH + h) * SS + s) * HD + (n & 63)] = val;
                } else {
                    C[(size_t)m * DD + n] = val;
                }
            }
        }
    }
}

// ---------------- Flash attention (fp32), Q/K/V in [B,H,S,HD] ----------------
#define TQ 32
#define TK 64

__global__ __launch_bounds__(256)
void attn_kernel(const float* __restrict__ Q, const float* __restrict__ K,
                 const float* __restrict__ V, const int* __restrict__ mask,
                 float* __restrict__ O)
{
    __shared__ float Qt[HD][TQ + 2];
    __shared__ float Kt[HD][TK + 4];
    __shared__ float Vs[TK][HD + 4];
    __shared__ float Pt[TK][TQ + 2];
    __shared__ float pmax[8][TQ];
    __shared__ float psum[8][TQ];
    __shared__ float mrow[TQ];
    __shared__ float arow[TQ];
    __shared__ float linv[TQ];

    const int tid = threadIdx.x;
    const int tx = tid & 15;
    const int ty = tid >> 4;
    const int q0 = blockIdx.x * TQ;
    const int h  = blockIdx.y;
    const int b  = blockIdx.z;

    const float* Qbh = Q + (size_t)(b * HH + h) * SS * HD;
    const float* Kbh = K + (size_t)(b * HH + h) * SS * HD;
    const float* Vbh = V + (size_t)(b * HH + h) * SS * HD;

#pragma unroll
    for (int t = 0; t < 2; ++t) {
        const int idx = tid + t * 256;
        const int r  = idx >> 4;
        const int d4 = (idx & 15) << 2;
        const float4 v = *(const float4*)(Qbh + (size_t)(q0 + r) * HD + d4);
        Qt[d4 + 0][r] = v.x;
        Qt[d4 + 1][r] = v.y;
        Qt[d4 + 2][r] = v.z;
        Qt[d4 + 3][r] = v.w;
    }

    float m_r = -INFINITY;
    float l_r = 0.0f;
    float acc[2][4];
#pragma unroll
    for (int i = 0; i < 2; ++i)
#pragma unroll
        for (int j = 0; j < 4; ++j) acc[i][j] = 0.0f;

    const int sr = tid & 31;
    const int sp = tid >> 5;

    for (int kt = 0; kt < SS / TK; ++kt) {
        const int k0 = kt * TK;
        __syncthreads();

#pragma unroll
        for (int t = 0; t < 4; ++t) {
            const int idx = tid + t * 256;
            const int r  = idx >> 4;
            const int d4 = (idx & 15) << 2;
            const float4 kv = *(const float4*)(Kbh + (size_t)(k0 + r) * HD + d4);
            Kt[d4 + 0][r] = kv.x;
            Kt[d4 + 1][r] = kv.y;
            Kt[d4 + 2][r] = kv.z;
            Kt[d4 + 3][r] = kv.w;
            const float4 vv = *(const float4*)(Vbh + (size_t)(k0 + r) * HD + d4);
            *(float4*)&Vs[r][d4] = vv;
        }
        __syncthreads();

        float s[2][4];
#pragma unroll
        for (int i = 0; i < 2; ++i)
#pragma unroll
            for (int j = 0; j < 4; ++j) s[i][j] = 0.0f;

#pragma unroll 16
        for (int d = 0; d < HD; ++d) {
            const float2 a = *(const float2*)&Qt[d][ty * 2];
            const float4 kv = *(const float4*)&Kt[d][tx * 4];
            s[0][0] = fmaf(a.x, kv.x, s[0][0]);
            s[0][1] = fmaf(a.x, kv.y, s[0][1]);
            s[0][2] = fmaf(a.x, kv.z, s[0][2]);
            s[0][3] = fmaf(a.x, kv.w, s[0][3]);
            s[1][0] = fmaf(a.y, kv.x, s[1][0]);
            s[1][1] = fmaf(a.y, kv.y, s[1][1]);
            s[1][2] = fmaf(a.y, kv.z, s[1][2]);
            s[1][3] = fmaf(a.y, kv.w, s[1][3]);
        }

        const int4 mv = *(const int4*)(mask + b * SS + k0 + tx * 4);
        const int mm[4] = {mv.x, mv.y, mv.z, mv.w};
#pragma unroll
        for (int j = 0; j < 4; ++j) {
            const float v0 = (mm[j] == 0) ? -1.0e9f : s[0][j] * 0.125f;
            const float v1 = (mm[j] == 0) ? -1.0e9f : s[1][j] * 0.125f;
            Pt[tx * 4 + j][ty * 2 + 0] = v0;
            Pt[tx * 4 + j][ty * 2 + 1] = v1;
        }
        __syncthreads();

        {
            float pm = -INFINITY;
#pragma unroll
            for (int u = 0; u < 8; ++u) pm = fmaxf(pm, Pt[sp * 8 + u][sr]);
            pmax[sp][sr] = pm;
        }
        __syncthreads();

        if (tid < TQ) {
            float mt = m_r;
#pragma unroll
            for (int p = 0; p < 8; ++p) mt = fmaxf(mt, pmax[p][tid]);
            const float a = __expf(m_r - mt);
            m_r = mt;
            mrow[tid] = mt;
            arow[tid] = a;
        }
        __syncthreads();

        {
            const float mloc = mrow[sr];
            float ps = 0.0f;
#pragma unroll
            for (int u = 0; u < 8; ++u) {
                const float e = __expf(Pt[sp * 8 + u][sr] - mloc);
                Pt[sp * 8 + u][sr] = e;
                ps += e;
            }
            psum[sp][sr] = ps;
        }
        __syncthreads();

        if (tid < TQ) {
            float ssum = 0.0f;
#pragma unroll
            for (int p = 0; p < 8; ++p) ssum += psum[p][tid];
            l_r = l_r * arow[tid] + ssum;
        }

        const float al0 = arow[ty * 2 + 0];
        const float al1 = arow[ty * 2 + 1];
#pragma unroll
        for (int j = 0; j < 4; ++j) { acc[0][j] *= al0; acc[1][j] *= al1; }

#pragma unroll 16
        for (int k = 0; k < TK; ++k) {
            const float2 a = *(const float2*)&Pt[k][ty * 2];
            const float4 v = *(const float4*)&Vs[k][tx * 4];
            acc[0][0] = fmaf(a.x, v.x, acc[0][0]);
            acc[0][1] = fmaf(a.x, v.y, acc[0][1]);
            acc[0][2] = fmaf(a.x, v.z, acc[0][2]);
            acc[0][3] = fmaf(a.x, v.w, acc[0][3]);
            acc[1][0] = fmaf(a.y, v.x, acc[1][0]);
            acc[1][1] = fmaf(a.y, v.y, acc[1][1]);
            acc[1][2] = fmaf(a.y, v.z, acc[1][2]);
            acc[1][3] = fmaf(a.y, v.w, acc[1][3]);
        }
    }

    if (tid < TQ) linv[tid] = 1.0f / l_r;
    __syncthreads();

#pragma unroll
    for (int i = 0; i < 2; ++i) {
        const int q = ty * 2 + i;
        const float li = linv[q];
        float4 o;
        o.x = acc[i][0] * li;
        o.y = acc[i][1] * li;
        o.z = acc[i][2] * li;
        o.w = acc[i][3] * li;
        *(float4*)(O + (size_t)(b * SS + q0 + q) * DD + h * HD + tx * 4) = o;
    }
}

extern "C" void kernel_launch(void* const* d_in, const int* in_sizes, int n_in,
                              void* d_out, int out_size, void* d_ws, size_t ws_size,
                              hipStream_t stream) {
    const float* xq   = (const float*)d_in[0];
    const float* xk   = (const float*)d_in[1];
    const float* xv   = (const float*)d_in[2];
    const int*   mask = (const int*)d_in[3];
    const float* wq   = (const float*)d_in[4];
    const float* bq   = (const float*)d_in[5];
    const float* wk   = (const float*)d_in[6];
    const float* bk   = (const float*)d_in[7];
    const float* wv   = (const float*)d_in[8];
    const float* bv   = (const float*)d_in[9];
    const float* wo   = (const float*)d_in[10];
    const float* bo   = (const float*)d_in[11];
    float* out = (float*)d_out;

    float* ws = (float*)d_ws;
    const size_t n = (size_t)BB * SS * DD;   // 4,194,304 floats (16 MB)
    // Q-heads live in d_out (consumed by attn_kernel before final GEMM
    // overwrites d_out — stream-ordered). d_ws holds K, V, Oa = 48 MB.
    float* Qh = out;
    float* Kh = ws;
    float* Vh = ws + n;
    float* Oa = ws + 2 * n;

    dim3 gg(DD / BN, (BB * SS) / BM);   // (16, 32) = 512 blocks
    gemm_bias_mfma<<<gg, 256, 0, stream>>>(xq, wq, bq, Qh, 1);
    gemm_bias_mfma<<<gg, 256, 0, stream>>>(xk, wk, bk, Kh, 1);
    gemm_bias_mfma<<<gg, 256, 0, stream>>>(xv, wv, bv, Vh, 1);

    dim3 ga(SS / TQ, HH, BB);           // (64, 16, 2)
    attn_kernel<<<ga, 256, 0, stream>>>(Qh, Kh, Vh, mask, Oa);

    gemm_bias_mfma<<<gg, 256, 0, stream>>>(Oa, wo, bo, out, 0);
}

// Round 4
// 559.176 us; speedup vs baseline: 2.3985x; 1.8697x over previous
//
#include <hip/hip_runtime.h>
#include <math.h>

#define BB 2
#define SS 2048
#define DD 1024
#define HH 16
#define HD 64

typedef short short8 __attribute__((ext_vector_type(8)));
typedef float floatx4 __attribute__((ext_vector_type(4)));

__device__ inline ushort f2bf_rne(float x) {
    union { float f; unsigned u; } v; v.f = x;
    unsigned r = v.u + 0x7FFFu + ((v.u >> 16) & 1u);
    return (ushort)(r >> 16);
}
__device__ inline float bf2f(ushort h) {
    union { unsigned u; float f; } v; v.u = ((unsigned)h) << 16;
    return v.f;
}
// split 8 floats into hi/lo bf16 fragments
__device__ inline void split8(const float* x, short8& h8, short8& l8) {
#pragma unroll
    for (int j = 0; j < 8; ++j) {
        const ushort hh = f2bf_rne(x[j]);
        h8[j] = (short)hh;
        l8[j] = (short)f2bf_rne(x[j] - bf2f(hh));
    }
}

// ---------------- Split-bf16 MFMA GEMM: C = X @ W^T + bias ----------------
#define BM 128
#define BN 64
#define BK 32
#define LDK 40

__global__ __launch_bounds__(256, 2)
void gemm_bias_mfma(const float* __restrict__ X, const float* __restrict__ W,
                    const float* __restrict__ bias, float* __restrict__ C,
                    int split)
{
    __shared__ ushort Ah[BM][LDK];
    __shared__ ushort Al[BM][LDK];
    __shared__ ushort Bh[BN][LDK];
    __shared__ ushort Bl[BN][LDK];

    const int tid  = threadIdx.x;
    const int lane = tid & 63;
    const int wave = tid >> 6;
    const int wr = wave >> 1;
    const int wc = wave & 1;
    const int lt = lane & 15;
    const int lq = lane >> 4;
    const int m0 = blockIdx.y * BM;
    const int n0 = blockIdx.x * BN;

    floatx4 acc[4][2];
#pragma unroll
    for (int mi = 0; mi < 4; ++mi)
#pragma unroll
        for (int ni = 0; ni < 2; ++ni) acc[mi][ni] = (floatx4)0.0f;

    const int ar[4] = { (tid + 0*256) >> 3, (tid + 1*256) >> 3,
                        (tid + 2*256) >> 3, (tid + 3*256) >> 3 };
    const int ak = (tid & 7) * 4;

    for (int k0 = 0; k0 < DD; k0 += BK) {
        float4 av[4], bv[2];
#pragma unroll
        for (int t = 0; t < 4; ++t)
            av[t] = *(const float4*)(X + (size_t)(m0 + ar[t]) * DD + k0 + ak);
#pragma unroll
        for (int t = 0; t < 2; ++t)
            bv[t] = *(const float4*)(W + (size_t)(n0 + ar[t]) * DD + k0 + ak);

        __syncthreads();

#pragma unroll
        for (int t = 0; t < 4; ++t) {
            const float x[4] = {av[t].x, av[t].y, av[t].z, av[t].w};
            ushort4 h, l;
            ushort* hp = (ushort*)&h; ushort* lp = (ushort*)&l;
#pragma unroll
            for (int j = 0; j < 4; ++j) {
                const ushort hh = f2bf_rne(x[j]);
                hp[j] = hh;
                lp[j] = f2bf_rne(x[j] - bf2f(hh));
            }
            *(ushort4*)&Ah[ar[t]][ak] = h;
            *(ushort4*)&Al[ar[t]][ak] = l;
        }
#pragma unroll
        for (int t = 0; t < 2; ++t) {
            const float x[4] = {bv[t].x, bv[t].y, bv[t].z, bv[t].w};
            ushort4 h, l;
            ushort* hp = (ushort*)&h; ushort* lp = (ushort*)&l;
#pragma unroll
            for (int j = 0; j < 4; ++j) {
                const ushort hh = f2bf_rne(x[j]);
                hp[j] = hh;
                lp[j] = f2bf_rne(x[j] - bf2f(hh));
            }
            *(ushort4*)&Bh[ar[t]][ak] = h;
            *(ushort4*)&Bl[ar[t]][ak] = l;
        }
        __syncthreads();

        short8 a_h[4], a_l[4], b_h[2], b_l[2];
#pragma unroll
        for (int mi = 0; mi < 4; ++mi) {
            const int row = wr * 64 + mi * 16 + lt;
            a_h[mi] = *(const short8*)&Ah[row][lq * 8];
            a_l[mi] = *(const short8*)&Al[row][lq * 8];
        }
#pragma unroll
        for (int ni = 0; ni < 2; ++ni) {
            const int row = wc * 32 + ni * 16 + lt;
            b_h[ni] = *(const short8*)&Bh[row][lq * 8];
            b_l[ni] = *(const short8*)&Bl[row][lq * 8];
        }

#pragma unroll
        for (int mi = 0; mi < 4; ++mi)
#pragma unroll
            for (int ni = 0; ni < 2; ++ni) {
                acc[mi][ni] = __builtin_amdgcn_mfma_f32_16x16x32_bf16(a_h[mi], b_h[ni], acc[mi][ni], 0, 0, 0);
                acc[mi][ni] = __builtin_amdgcn_mfma_f32_16x16x32_bf16(a_h[mi], b_l[ni], acc[mi][ni], 0, 0, 0);
                acc[mi][ni] = __builtin_amdgcn_mfma_f32_16x16x32_bf16(a_l[mi], b_h[ni], acc[mi][ni], 0, 0, 0);
            }
    }

    const float bias0 = bias[n0 + wc * 32 + lt];
    const float bias1 = bias[n0 + wc * 32 + 16 + lt];
#pragma unroll
    for (int mi = 0; mi < 4; ++mi) {
#pragma unroll
        for (int ni = 0; ni < 2; ++ni) {
            const int n = n0 + wc * 32 + ni * 16 + lt;
            const float bb = ni ? bias1 : bias0;
#pragma unroll
            for (int r = 0; r < 4; ++r) {
                const int m = m0 + wr * 64 + mi * 16 + lq * 4 + r;
                const float val = acc[mi][ni][r] + bb;
                if (split) {
                    const int b = m >> 11;
                    const int s = m & (SS - 1);
                    const int h = n >> 6;
                    C[(size_t)((b * HH + h) * SS + s) * HD + (n & 63)] = val;
                } else {
                    C[(size_t)m * DD + n] = val;
                }
            }
        }
    }
}

// ---------------- MFMA flash attention ----------------
// Q/K/V in [B,H,S,HD] fp32. Block: 128 Q-rows, 4 waves x 32 rows.
// QK^T: split-bf16 (3 MFMA), frags direct from global. PV: bf16 P via
// per-wave-private LDS roundtrip, V^T staged to LDS (double-buffered,
// 1 barrier/K-tile). O written [B,S,D].
#define ATQ 128
#define LDV 72
#define LDP 72

__global__ __launch_bounds__(256, 2)
void attn_mfma(const float* __restrict__ Q, const float* __restrict__ K,
               const float* __restrict__ V, const int* __restrict__ mask,
               float* __restrict__ O)
{
    __shared__ __align__(16) ushort Vt[2][HD][LDV];   // V^T: [dim][key]
    __shared__ __align__(16) ushort Pw[4][32][LDP];   // per-wave P: [row][key]

    const int tid  = threadIdx.x;
    const int lane = tid & 63;
    const int wave = tid >> 6;
    const int lt = lane & 15;
    const int lq = lane >> 4;
    const int q0 = blockIdx.x * ATQ;
    const int h  = blockIdx.y;
    const int b  = blockIdx.z;

    const float* Qbh = Q + (size_t)(b * HH + h) * SS * HD;
    const float* Kbh = K + (size_t)(b * HH + h) * SS * HD;
    const float* Vbh = V + (size_t)(b * HH + h) * SS * HD;

    // Q fragments (A-layout: A[m=lt][k=lq*8+j]), split hi/lo, held in regs
    short8 qh[2][2], ql[2][2];
#pragma unroll
    for (int mt = 0; mt < 2; ++mt)
#pragma unroll
        for (int ks = 0; ks < 2; ++ks) {
            const float* p = Qbh + (size_t)(q0 + wave * 32 + mt * 16 + lt) * HD + ks * 32 + lq * 8;
            float x[8];
            *(float4*)&x[0] = *(const float4*)p;
            *(float4*)&x[4] = *(const float4*)(p + 4);
            split8(x, qh[mt][ks], ql[mt][ks]);
        }

    floatx4 oacc[2][4];
#pragma unroll
    for (int mt = 0; mt < 2; ++mt)
#pragma unroll
        for (int dt = 0; dt < 4; ++dt) oacc[mt][dt] = (floatx4)0.0f;

    float mrow[2][4], lrow[2][4];
#pragma unroll
    for (int mt = 0; mt < 2; ++mt)
#pragma unroll
        for (int r = 0; r < 4; ++r) { mrow[mt][r] = -INFINITY; lrow[mt][r] = 0.0f; }

    for (int kt = 0; kt < SS / 64; ++kt) {
        const int k0 = kt * 64;
        const int buf = kt & 1;

        // ---- stage V^T (bf16): lane=key, wave covers 16 dims; conflict-free writes
        {
            const float* vp = Vbh + (size_t)(k0 + lane) * HD + wave * 16;
            float x[16];
            *(float4*)&x[0]  = *(const float4*)(vp + 0);
            *(float4*)&x[4]  = *(const float4*)(vp + 4);
            *(float4*)&x[8]  = *(const float4*)(vp + 8);
            *(float4*)&x[12] = *(const float4*)(vp + 12);
#pragma unroll
            for (int e = 0; e < 16; ++e)
                Vt[buf][wave * 16 + e][lane] = f2bf_rne(x[e]);
        }
        __syncthreads();

        // ---- QK^T: S-tile 32x64 per wave, split-bf16
        floatx4 sacc[2][4];
#pragma unroll
        for (int mt = 0; mt < 2; ++mt)
#pragma unroll
            for (int nt = 0; nt < 4; ++nt) sacc[mt][nt] = (floatx4)0.0f;

#pragma unroll
        for (int nt = 0; nt < 4; ++nt) {
            const float* kp = Kbh + (size_t)(k0 + nt * 16 + lt) * HD + lq * 8;
            float x0[8], x1[8];
            *(float4*)&x0[0] = *(const float4*)kp;
            *(float4*)&x0[4] = *(const float4*)(kp + 4);
            *(float4*)&x1[0] = *(const float4*)(kp + 32);
            *(float4*)&x1[4] = *(const float4*)(kp + 36);
            short8 kh0, kl0, kh1, kl1;
            split8(x0, kh0, kl0);
            split8(x1, kh1, kl1);
#pragma unroll
            for (int mt = 0; mt < 2; ++mt) {
                floatx4 a = sacc[mt][nt];
                a = __builtin_amdgcn_mfma_f32_16x16x32_bf16(qh[mt][0], kh0, a, 0, 0, 0);
                a = __builtin_amdgcn_mfma_f32_16x16x32_bf16(qh[mt][0], kl0, a, 0, 0, 0);
                a = __builtin_amdgcn_mfma_f32_16x16x32_bf16(ql[mt][0], kh0, a, 0, 0, 0);
                a = __builtin_amdgcn_mfma_f32_16x16x32_bf16(qh[mt][1], kh1, a, 0, 0, 0);
                a = __builtin_amdgcn_mfma_f32_16x16x32_bf16(qh[mt][1], kl1, a, 0, 0, 0);
                a = __builtin_amdgcn_mfma_f32_16x16x32_bf16(ql[mt][1], kh1, a, 0, 0, 0);
                sacc[mt][nt] = a;
            }
        }

        // ---- mask + scale (C-layout: col=nt*16+lt, row=lq*4+r)
        int msk[4];
#pragma unroll
        for (int nt = 0; nt < 4; ++nt) msk[nt] = mask[b * SS + k0 + nt * 16 + lt];
#pragma unroll
        for (int mt = 0; mt < 2; ++mt)
#pragma unroll
            for (int nt = 0; nt < 4; ++nt)
#pragma unroll
                for (int r = 0; r < 4; ++r)
                    sacc[mt][nt][r] = (msk[nt] == 0) ? -1.0e9f : sacc[mt][nt][r] * 0.125f;

        // ---- online softmax per row (16-lane groups share a row)
        float al[2][4];
#pragma unroll
        for (int mt = 0; mt < 2; ++mt)
#pragma unroll
            for (int r = 0; r < 4; ++r) {
                float v = fmaxf(fmaxf(sacc[mt][0][r], sacc[mt][1][r]),
                                fmaxf(sacc[mt][2][r], sacc[mt][3][r]));
                v = fmaxf(v, __shfl_xor(v, 1));
                v = fmaxf(v, __shfl_xor(v, 2));
                v = fmaxf(v, __shfl_xor(v, 4));
                v = fmaxf(v, __shfl_xor(v, 8));
                const float mnew = fmaxf(mrow[mt][r], v);
                const float a = __expf(mrow[mt][r] - mnew);   // exp(-inf)=0 first tile
                mrow[mt][r] = mnew;
                al[mt][r] = a;
                float ls = 0.0f;
#pragma unroll
                for (int nt = 0; nt < 4; ++nt) {
                    const float p = __expf(sacc[mt][nt][r] - mnew);
                    sacc[mt][nt][r] = p;
                    ls += p;
                }
                ls += __shfl_xor(ls, 1);
                ls += __shfl_xor(ls, 2);
                ls += __shfl_xor(ls, 4);
                ls += __shfl_xor(ls, 8);
                lrow[mt][r] = lrow[mt][r] * a + ls;
            }

        // rescale O accumulator
#pragma unroll
        for (int mt = 0; mt < 2; ++mt)
#pragma unroll
            for (int dt = 0; dt < 4; ++dt)
#pragma unroll
                for (int r = 0; r < 4; ++r) oacc[mt][dt][r] *= al[mt][r];

        // ---- P: C-layout -> A-layout via per-wave-private LDS (no barrier)
#pragma unroll
        for (int mt = 0; mt < 2; ++mt)
#pragma unroll
            for (int nt = 0; nt < 4; ++nt)
#pragma unroll
                for (int r = 0; r < 4; ++r)
                    Pw[wave][mt * 16 + lq * 4 + r][nt * 16 + lt] =
                        f2bf_rne(sacc[mt][nt][r]);

        short8 pa[2][2];
#pragma unroll
        for (int mt = 0; mt < 2; ++mt)
#pragma unroll
            for (int ks = 0; ks < 2; ++ks)
                pa[mt][ks] = *(const short8*)&Pw[wave][mt * 16 + lt][ks * 32 + lq * 8];

        // ---- PV: O += P @ V  (B-frag: B[n=dim=dt*16+lt][k=key=ks*32+lq*8])
#pragma unroll
        for (int dt = 0; dt < 4; ++dt)
#pragma unroll
            for (int ks = 0; ks < 2; ++ks) {
                const short8 vb = *(const short8*)&Vt[buf][dt * 16 + lt][ks * 32 + lq * 8];
#pragma unroll
                for (int mt = 0; mt < 2; ++mt)
                    oacc[mt][dt] = __builtin_amdgcn_mfma_f32_16x16x32_bf16(pa[mt][ks], vb, oacc[mt][dt], 0, 0, 0);
            }
    }

    // ---- epilogue: normalize, write O as [B,S,D]
#pragma unroll
    for (int mt = 0; mt < 2; ++mt) {
        float linv[4];
#pragma unroll
        for (int r = 0; r < 4; ++r) linv[r] = 1.0f / lrow[mt][r];
#pragma unroll
        for (int dt = 0; dt < 4; ++dt)
#pragma unroll
            for (int r = 0; r < 4; ++r) {
                const int row = q0 + wave * 32 + mt * 16 + lq * 4 + r;
                O[(size_t)(b * SS + row) * DD + h * HD + dt * 16 + lt] =
                    oacc[mt][dt][r] * linv[r];
            }
    }
}

extern "C" void kernel_launch(void* const* d_in, const int* in_sizes, int n_in,
                              void* d_out, int out_size, void* d_ws, size_t ws_size,
                              hipStream_t stream) {
    const float* xq   = (const float*)d_in[0];
    const float* xk   = (const float*)d_in[1];
    const float* xv   = (const float*)d_in[2];
    const int*   mask = (const int*)d_in[3];
    const float* wq   = (const float*)d_in[4];
    const float* bq   = (const float*)d_in[5];
    const float* wk   = (const float*)d_in[6];
    const float* bk   = (const float*)d_in[7];
    const float* wv   = (const float*)d_in[8];
    const float* bv   = (const float*)d_in[9];
    const float* wo   = (const float*)d_in[10];
    const float* bo   = (const float*)d_in[11];
    float* out = (float*)d_out;

    float* ws = (float*)d_ws;
    const size_t n = (size_t)BB * SS * DD;
    float* Qh = out;          // consumed by attn before final GEMM overwrites
    float* Kh = ws;
    float* Vh = ws + n;
    float* Oa = ws + 2 * n;

    dim3 gg(DD / BN, (BB * SS) / BM);
    gemm_bias_mfma<<<gg, 256, 0, stream>>>(xq, wq, bq, Qh, 1);
    gemm_bias_mfma<<<gg, 256, 0, stream>>>(xk, wk, bk, Kh, 1);
    gemm_bias_mfma<<<gg, 256, 0, stream>>>(xv, wv, bv, Vh, 1);

    dim3 ga(SS / ATQ, HH, BB);   // (16, 16, 2) = 512 blocks
    attn_mfma<<<ga, 256, 0, stream>>>(Qh, Kh, Vh, mask, Oa);

    gemm_bias_mfma<<<gg, 256, 0, stream>>>(Oa, wo, bo, out, 0);
}

// Round 5
// 505.848 us; speedup vs baseline: 2.6513x; 1.1054x over previous
//
#include <hip/hip_runtime.h>
#include <math.h>

#define BB 2
#define SS 2048
#define DD 1024
#define HH 16
#define HD 64

typedef short short8 __attribute__((ext_vector_type(8)));
typedef float floatx4 __attribute__((ext_vector_type(4)));

__device__ inline ushort f2bf_rne(float x) {
    union { float f; unsigned u; } v; v.f = x;
    unsigned r = v.u + 0x7FFFu + ((v.u >> 16) & 1u);
    return (ushort)(r >> 16);
}
__device__ inline float bf2f(ushort h) {
    union { unsigned u; float f; } v; v.u = ((unsigned)h) << 16;
    return v.f;
}

// ---------------- Split-bf16 MFMA GEMM: C = X @ W^T + bias ----------------
// mode 0: fp32 C[m][n] -> Cf[m*DD+n]
// mode 1: val=(acc+bias)*oscale split into hi/lo bf16 -> Chi/Clo at [B,H,S,HD]
// mode 2: val=(acc+bias) as bf16 -> Chi at [B,H,HD,S]  (V transposed)
#define BM 128
#define BN 64
#define BK 32
#define LDK 40

__global__ __launch_bounds__(256, 2)
void gemm_bias_mfma(const float* __restrict__ X, const float* __restrict__ W,
                    const float* __restrict__ bias, float* __restrict__ Cf,
                    ushort* __restrict__ Chi, ushort* __restrict__ Clo,
                    int mode, float oscale)
{
    __shared__ ushort Ah[BM][LDK];
    __shared__ ushort Al[BM][LDK];
    __shared__ ushort Bh[BN][LDK];
    __shared__ ushort Bl[BN][LDK];

    const int tid  = threadIdx.x;
    const int lane = tid & 63;
    const int wave = tid >> 6;
    const int wr = wave >> 1;
    const int wc = wave & 1;
    const int lt = lane & 15;
    const int lq = lane >> 4;
    const int m0 = blockIdx.y * BM;
    const int n0 = blockIdx.x * BN;

    floatx4 acc[4][2];
#pragma unroll
    for (int mi = 0; mi < 4; ++mi)
#pragma unroll
        for (int ni = 0; ni < 2; ++ni) acc[mi][ni] = (floatx4)0.0f;

    const int ar[4] = { (tid + 0*256) >> 3, (tid + 1*256) >> 3,
                        (tid + 2*256) >> 3, (tid + 3*256) >> 3 };
    const int ak = (tid & 7) * 4;

    for (int k0 = 0; k0 < DD; k0 += BK) {
        float4 av[4], bv[2];
#pragma unroll
        for (int t = 0; t < 4; ++t)
            av[t] = *(const float4*)(X + (size_t)(m0 + ar[t]) * DD + k0 + ak);
#pragma unroll
        for (int t = 0; t < 2; ++t)
            bv[t] = *(const float4*)(W + (size_t)(n0 + ar[t]) * DD + k0 + ak);

        __syncthreads();

#pragma unroll
        for (int t = 0; t < 4; ++t) {
            const float x[4] = {av[t].x, av[t].y, av[t].z, av[t].w};
            ushort4 h, l;
            ushort* hp = (ushort*)&h; ushort* lp = (ushort*)&l;
#pragma unroll
            for (int j = 0; j < 4; ++j) {
                const ushort hh = f2bf_rne(x[j]);
                hp[j] = hh;
                lp[j] = f2bf_rne(x[j] - bf2f(hh));
            }
            *(ushort4*)&Ah[ar[t]][ak] = h;
            *(ushort4*)&Al[ar[t]][ak] = l;
        }
#pragma unroll
        for (int t = 0; t < 2; ++t) {
            const float x[4] = {bv[t].x, bv[t].y, bv[t].z, bv[t].w};
            ushort4 h, l;
            ushort* hp = (ushort*)&h; ushort* lp = (ushort*)&l;
#pragma unroll
            for (int j = 0; j < 4; ++j) {
                const ushort hh = f2bf_rne(x[j]);
                hp[j] = hh;
                lp[j] = f2bf_rne(x[j] - bf2f(hh));
            }
            *(ushort4*)&Bh[ar[t]][ak] = h;
            *(ushort4*)&Bl[ar[t]][ak] = l;
        }
        __syncthreads();

        short8 a_h[4], a_l[4], b_h[2], b_l[2];
#pragma unroll
        for (int mi = 0; mi < 4; ++mi) {
            const int row = wr * 64 + mi * 16 + lt;
            a_h[mi] = *(const short8*)&Ah[row][lq * 8];
            a_l[mi] = *(const short8*)&Al[row][lq * 8];
        }
#pragma unroll
        for (int ni = 0; ni < 2; ++ni) {
            const int row = wc * 32 + ni * 16 + lt;
            b_h[ni] = *(const short8*)&Bh[row][lq * 8];
            b_l[ni] = *(const short8*)&Bl[row][lq * 8];
        }

#pragma unroll
        for (int mi = 0; mi < 4; ++mi)
#pragma unroll
            for (int ni = 0; ni < 2; ++ni) {
                acc[mi][ni] = __builtin_amdgcn_mfma_f32_16x16x32_bf16(a_h[mi], b_h[ni], acc[mi][ni], 0, 0, 0);
                acc[mi][ni] = __builtin_amdgcn_mfma_f32_16x16x32_bf16(a_h[mi], b_l[ni], acc[mi][ni], 0, 0, 0);
                acc[mi][ni] = __builtin_amdgcn_mfma_f32_16x16x32_bf16(a_l[mi], b_h[ni], acc[mi][ni], 0, 0, 0);
            }
    }

    const float bias0 = bias[n0 + wc * 32 + lt];
    const float bias1 = bias[n0 + wc * 32 + 16 + lt];
#pragma unroll
    for (int mi = 0; mi < 4; ++mi) {
#pragma unroll
        for (int ni = 0; ni < 2; ++ni) {
            const int n = n0 + wc * 32 + ni * 16 + lt;
            const float bb = ni ? bias1 : bias0;
            if (mode == 0) {
#pragma unroll
                for (int r = 0; r < 4; ++r) {
                    const int m = m0 + wr * 64 + mi * 16 + lq * 4 + r;
                    Cf[(size_t)m * DD + n] = acc[mi][ni][r] + bb;
                }
            } else if (mode == 1) {
#pragma unroll
                for (int r = 0; r < 4; ++r) {
                    const int m = m0 + wr * 64 + mi * 16 + lq * 4 + r;
                    const int b = m >> 11;
                    const int s = m & (SS - 1);
                    const int h = n >> 6;
                    const float val = (acc[mi][ni][r] + bb) * oscale;
                    const ushort hh = f2bf_rne(val);
                    const size_t addr = (size_t)((b * HH + h) * SS + s) * HD + (n & 63);
                    Chi[addr] = hh;
                    Clo[addr] = f2bf_rne(val - bf2f(hh));
                }
            } else {
                // mode 2: bf16 V^T [B,H,HD,S]; 4 consecutive s -> ushort4
                const int mb = m0 + wr * 64 + mi * 16 + lq * 4;
                const int b = mb >> 11;
                const int s = mb & (SS - 1);
                const int h = n >> 6;
                ushort4 pack;
                pack.x = f2bf_rne(acc[mi][ni][0] + bb);
                pack.y = f2bf_rne(acc[mi][ni][1] + bb);
                pack.z = f2bf_rne(acc[mi][ni][2] + bb);
                pack.w = f2bf_rne(acc[mi][ni][3] + bb);
                *(ushort4*)&Chi[(size_t)((b * HH + h) * HD + (n & 63)) * SS + s] = pack;
            }
        }
    }
}

// ---------------- MFMA flash attention (barrier-free) ----------------
// Qhi/Qlo, Khi/Klo: bf16 split [B,H,S,HD] (Q pre-scaled by 0.125*log2e).
// Vt: bf16 [B,H,HD,S]. All A/B frags load directly from global.
// P: C->A layout via per-wave-private LDS (no __syncthreads anywhere).
// l-rowsum via MFMA against all-ones B frag. exp via exp2f (native v_exp).
#define ATQ 128
#define LDP 72

__global__ __launch_bounds__(256, 2)
void attn_mfma(const ushort* __restrict__ Qhi, const ushort* __restrict__ Qlo,
               const ushort* __restrict__ Khi, const ushort* __restrict__ Klo,
               const ushort* __restrict__ Vt, const int* __restrict__ mask,
               float* __restrict__ O)
{
    __shared__ __align__(16) ushort Pw[4][32][LDP];

    const int tid  = threadIdx.x;
    const int lane = tid & 63;
    const int wave = tid >> 6;
    const int lt = lane & 15;
    const int lq = lane >> 4;
    const int q0 = blockIdx.x * ATQ;
    const int h  = blockIdx.y;
    const int b  = blockIdx.z;

    const size_t bh   = (size_t)(b * HH + h);
    const size_t sbase = bh * SS * HD;          // Q/K [B,H,S,HD] base (elements)
    const size_t vbase = bh * HD * SS;          // V^T [B,H,HD,S] base

    short8 ones;
#pragma unroll
    for (int j = 0; j < 8; ++j) ones[j] = (short)0x3F80;   // bf16 1.0

    // Q frags (A-layout: A[m=lt][k=lq*8+j]), pre-scaled+split in GEMM
    short8 qh[2][2], ql[2][2];
#pragma unroll
    for (int mt = 0; mt < 2; ++mt)
#pragma unroll
        for (int ks = 0; ks < 2; ++ks) {
            const size_t off = sbase + (size_t)(q0 + wave * 32 + mt * 16 + lt) * HD + ks * 32 + lq * 8;
            qh[mt][ks] = *(const short8*)(Qhi + off);
            ql[mt][ks] = *(const short8*)(Qlo + off);
        }

    floatx4 oacc[2][4];
#pragma unroll
    for (int mt = 0; mt < 2; ++mt)
#pragma unroll
        for (int dt = 0; dt < 4; ++dt) oacc[mt][dt] = (floatx4)0.0f;

    float mrow[2][4], lrow[2][4];
#pragma unroll
    for (int mt = 0; mt < 2; ++mt)
#pragma unroll
        for (int r = 0; r < 4; ++r) { mrow[mt][r] = -INFINITY; lrow[mt][r] = 0.0f; }

    for (int kt = 0; kt < SS / 64; ++kt) {
        const int k0 = kt * 64;

        // ---- QK^T (split-bf16: qh*kh + qh*kl + ql*kh), K frags from global
        floatx4 sacc[2][4];
#pragma unroll
        for (int mt = 0; mt < 2; ++mt)
#pragma unroll
            for (int nt = 0; nt < 4; ++nt) sacc[mt][nt] = (floatx4)0.0f;

#pragma unroll
        for (int nt = 0; nt < 4; ++nt) {
            const size_t koff = sbase + (size_t)(k0 + nt * 16 + lt) * HD + lq * 8;
            const short8 kh0 = *(const short8*)(Khi + koff);
            const short8 kh1 = *(const short8*)(Khi + koff + 32);
            const short8 kl0 = *(const short8*)(Klo + koff);
            const short8 kl1 = *(const short8*)(Klo + koff + 32);
#pragma unroll
            for (int mt = 0; mt < 2; ++mt) {
                floatx4 a = sacc[mt][nt];
                a = __builtin_amdgcn_mfma_f32_16x16x32_bf16(qh[mt][0], kh0, a, 0, 0, 0);
                a = __builtin_amdgcn_mfma_f32_16x16x32_bf16(qh[mt][0], kl0, a, 0, 0, 0);
                a = __builtin_amdgcn_mfma_f32_16x16x32_bf16(ql[mt][0], kh0, a, 0, 0, 0);
                a = __builtin_amdgcn_mfma_f32_16x16x32_bf16(qh[mt][1], kh1, a, 0, 0, 0);
                a = __builtin_amdgcn_mfma_f32_16x16x32_bf16(qh[mt][1], kl1, a, 0, 0, 0);
                a = __builtin_amdgcn_mfma_f32_16x16x32_bf16(ql[mt][1], kh1, a, 0, 0, 0);
                sacc[mt][nt] = a;
            }
        }

        // ---- mask (scores already in log2 domain via Q pre-scale)
        int msk[4];
#pragma unroll
        for (int nt = 0; nt < 4; ++nt) msk[nt] = mask[b * SS + k0 + nt * 16 + lt];
#pragma unroll
        for (int mt = 0; mt < 2; ++mt)
#pragma unroll
            for (int nt = 0; nt < 4; ++nt)
#pragma unroll
                for (int r = 0; r < 4; ++r)
                    sacc[mt][nt][r] = (msk[nt] == 0) ? -1.0e9f : sacc[mt][nt][r];

        // ---- online softmax (base-2); rows live in 16-lane groups
        float al[2][4];
#pragma unroll
        for (int mt = 0; mt < 2; ++mt)
#pragma unroll
            for (int r = 0; r < 4; ++r) {
                float v = fmaxf(fmaxf(sacc[mt][0][r], sacc[mt][1][r]),
                                fmaxf(sacc[mt][2][r], sacc[mt][3][r]));
                v = fmaxf(v, __shfl_xor(v, 1));
                v = fmaxf(v, __shfl_xor(v, 2));
                v = fmaxf(v, __shfl_xor(v, 4));
                v = fmaxf(v, __shfl_xor(v, 8));
                const float mnew = fmaxf(mrow[mt][r], v);
                al[mt][r] = exp2f(mrow[mt][r] - mnew);   // exp2(-inf)=0 first tile
                mrow[mt][r] = mnew;
#pragma unroll
                for (int nt = 0; nt < 4; ++nt)
                    sacc[mt][nt][r] = exp2f(sacc[mt][nt][r] - mnew);
            }

        // rescale O accumulator
#pragma unroll
        for (int mt = 0; mt < 2; ++mt)
#pragma unroll
            for (int dt = 0; dt < 4; ++dt)
#pragma unroll
                for (int r = 0; r < 4; ++r) oacc[mt][dt][r] *= al[mt][r];

        // ---- P: C-layout -> A-layout via wave-private LDS (no barrier)
#pragma unroll
        for (int mt = 0; mt < 2; ++mt)
#pragma unroll
            for (int nt = 0; nt < 4; ++nt)
#pragma unroll
                for (int r = 0; r < 4; ++r)
                    Pw[wave][mt * 16 + lq * 4 + r][nt * 16 + lt] =
                        f2bf_rne(sacc[mt][nt][r]);

        short8 pa[2][2];
#pragma unroll
        for (int mt = 0; mt < 2; ++mt)
#pragma unroll
            for (int ks = 0; ks < 2; ++ks)
                pa[mt][ks] = *(const short8*)&Pw[wave][mt * 16 + lt][ks * 32 + lq * 8];

        // ---- l-rowsum via MFMA with ones (consistent with bf16 P used in PV)
        floatx4 lsum[2];
#pragma unroll
        for (int mt = 0; mt < 2; ++mt) {
            floatx4 a = (floatx4)0.0f;
            a = __builtin_amdgcn_mfma_f32_16x16x32_bf16(pa[mt][0], ones, a, 0, 0, 0);
            a = __builtin_amdgcn_mfma_f32_16x16x32_bf16(pa[mt][1], ones, a, 0, 0, 0);
            lsum[mt] = a;
        }
#pragma unroll
        for (int mt = 0; mt < 2; ++mt)
#pragma unroll
            for (int r = 0; r < 4; ++r)
                lrow[mt][r] = lrow[mt][r] * al[mt][r] + lsum[mt][r];

        // ---- PV: O += P @ V, V^T frags direct from global
#pragma unroll
        for (int dt = 0; dt < 4; ++dt) {
            const size_t voff = vbase + (size_t)(dt * 16 + lt) * SS + k0 + lq * 8;
            const short8 vb0 = *(const short8*)(Vt + voff);
            const short8 vb1 = *(const short8*)(Vt + voff + 32);
#pragma unroll
            for (int mt = 0; mt < 2; ++mt) {
                oacc[mt][dt] = __builtin_amdgcn_mfma_f32_16x16x32_bf16(pa[mt][0], vb0, oacc[mt][dt], 0, 0, 0);
                oacc[mt][dt] = __builtin_amdgcn_mfma_f32_16x16x32_bf16(pa[mt][1], vb1, oacc[mt][dt], 0, 0, 0);
            }
        }
    }

    // ---- epilogue: normalize, write O as [B,S,D]
#pragma unroll
    for (int mt = 0; mt < 2; ++mt) {
        float linv[4];
#pragma unroll
        for (int r = 0; r < 4; ++r) linv[r] = 1.0f / lrow[mt][r];
#pragma unroll
        for (int dt = 0; dt < 4; ++dt)
#pragma unroll
            for (int r = 0; r < 4; ++r) {
                const int row = q0 + wave * 32 + mt * 16 + lq * 4 + r;
                O[(size_t)(b * SS + row) * DD + h * HD + dt * 16 + lt] =
                    oacc[mt][dt][r] * linv[r];
            }
    }
}

extern "C" void kernel_launch(void* const* d_in, const int* in_sizes, int n_in,
                              void* d_out, int out_size, void* d_ws, size_t ws_size,
                              hipStream_t stream) {
    const float* xq   = (const float*)d_in[0];
    const float* xk   = (const float*)d_in[1];
    const float* xv   = (const float*)d_in[2];
    const int*   mask = (const int*)d_in[3];
    const float* wq   = (const float*)d_in[4];
    const float* bq   = (const float*)d_in[5];
    const float* wk   = (const float*)d_in[6];
    const float* bk   = (const float*)d_in[7];
    const float* wv   = (const float*)d_in[8];
    const float* bv   = (const float*)d_in[9];
    const float* wo   = (const float*)d_in[10];
    const float* bo   = (const float*)d_in[11];
    float* out = (float*)d_out;

    const size_t n = (size_t)BB * SS * DD;   // 4,194,304 elements
    // Qhi/Qlo live in d_out (16 MB: 2 x 8 MB ushort) — fully consumed by
    // attn_mfma before the final GEMM overwrites d_out (stream-ordered).
    ushort* Qhi = (ushort*)out;
    ushort* Qlo = Qhi + n;
    // ws: Khi (8MB), Klo (8MB), Vt (8MB), Oa (16MB) = 40 MB
    ushort* Khi = (ushort*)d_ws;
    ushort* Klo = Khi + n;
    ushort* Vt  = Klo + n;
    float*  Oa  = (float*)(Vt + n);

    const float qscale = 0.125f * 1.44269504088896340736f;   // /sqrt(HD) * log2(e)

    dim3 gg(DD / BN, (BB * SS) / BM);
    gemm_bias_mfma<<<gg, 256, 0, stream>>>(xq, wq, bq, nullptr, Qhi, Qlo, 1, qscale);
    gemm_bias_mfma<<<gg, 256, 0, stream>>>(xk, wk, bk, nullptr, Khi, Klo, 1, 1.0f);
    gemm_bias_mfma<<<gg, 256, 0, stream>>>(xv, wv, bv, nullptr, Vt, nullptr, 2, 1.0f);

    dim3 ga(SS / ATQ, HH, BB);   // (16, 16, 2) = 512 blocks
    attn_mfma<<<ga, 256, 0, stream>>>(Qhi, Qlo, Khi, Klo, Vt, mask, Oa);

    gemm_bias_mfma<<<gg, 256, 0, stream>>>(Oa, wo, bo, out, nullptr, nullptr, 0, 1.0f);
}